// Round 1
// baseline (268.174 us; speedup 1.0000x reference)
//
#include <hip/hip_runtime.h>

typedef __bf16 bf16x8 __attribute__((ext_vector_type(8)));
typedef float f32x4 __attribute__((ext_vector_type(4)));
typedef unsigned short u16;

#define IN_F 4096
#define OUT_F 4096
#define NTOK 4096
#define RANK 32
#define KEXT 4128  /* 4096 + 32 lora columns */

// round-to-nearest-even f32 -> bf16 (no NaN handling needed here)
__device__ __forceinline__ u16 f2bf(float f) {
  union { float f; unsigned u; } c; c.f = f;
  unsigned u = c.u;
  return (u16)((u + 0x7FFFu + ((u >> 16) & 1u)) >> 16);
}

__device__ __forceinline__ void gload_lds16(const void* g, void* l) {
  __builtin_amdgcn_global_load_lds((const __attribute__((address_space(1))) void*)g,
                                   (__attribute__((address_space(3))) void*)l,
                                   16, 0, 0);
}

// ---------------- prep: per-token amax -> ascale, write bf16 int codes ----------------
__global__ __launch_bounds__(256) void prep_kernel(const float* __restrict__ x,
                                                   u16* __restrict__ A,
                                                   float* __restrict__ ascale) {
  int t = blockIdx.x;
  int tid = threadIdx.x;
  const float4* xr = (const float4*)(x + (size_t)t * IN_F);
  float4 v[4];
  float m = 0.f;
#pragma unroll
  for (int i = 0; i < 4; ++i) {
    v[i] = xr[tid + i * 256];
    m = fmaxf(m, fmaxf(fmaxf(fabsf(v[i].x), fabsf(v[i].y)),
                       fmaxf(fabsf(v[i].z), fabsf(v[i].w))));
  }
#pragma unroll
  for (int off = 32; off > 0; off >>= 1) m = fmaxf(m, __shfl_xor(m, off));
  __shared__ float wmax[4];
  if ((tid & 63) == 0) wmax[tid >> 6] = m;
  __syncthreads();
  m = fmaxf(fmaxf(wmax[0], wmax[1]), fmaxf(wmax[2], wmax[3]));
  float as = fmaxf(m, 1e-6f) / 7.f;
  float inv = 1.f / as;
  if (tid == 0) ascale[t] = as;
  u16* Ar = A + (size_t)t * KEXT;
#pragma unroll
  for (int i = 0; i < 4; ++i) {
    float q0 = fminf(fmaxf(rintf(v[i].x * inv), -8.f), 7.f);
    float q1 = fminf(fmaxf(rintf(v[i].y * inv), -8.f), 7.f);
    float q2 = fminf(fmaxf(rintf(v[i].z * inv), -8.f), 7.f);
    float q3 = fminf(fmaxf(rintf(v[i].w * inv), -8.f), 7.f);
    ushort4 u;
    u.x = f2bf(q0); u.y = f2bf(q1); u.z = f2bf(q2); u.w = f2bf(q3);
    *(ushort4*)(Ar + (size_t)(tid + i * 256) * 4) = u;
  }
}

// ---------------- dequant: int4 codes * group scale -> bf16, append lora_up ----------------
__global__ __launch_bounds__(256) void dequant_kernel(const int* __restrict__ qw,
                                                      const float* __restrict__ wscale,
                                                      const float* __restrict__ lu,
                                                      u16* __restrict__ B) {
  int o = blockIdx.x;
  int tid = threadIdx.x;
  const int4* qr = (const int4*)(qw + (size_t)o * IN_F);
  const float* sr = wscale + (size_t)o * (IN_F / 64);
  u16* Br = B + (size_t)o * KEXT;
#pragma unroll
  for (int s = 0; s < 4; ++s) {
    int e = tid + s * 256;       // int4 index; covers ints [4e, 4e+3], all in group e>>4
    int4 q = qr[e];
    float sc = sr[e >> 4];
    ushort4 u;
    u.x = f2bf((float)q.x * sc);
    u.y = f2bf((float)q.y * sc);
    u.z = f2bf((float)q.z * sc);
    u.w = f2bf((float)q.w * sc);
    *(ushort4*)(Br + (size_t)4 * e) = u;
  }
  if (tid < RANK) Br[IN_F + tid] = f2bf(lu[(size_t)o * RANK + tid]);
}

// ---------------- lorad: tr = x @ ld^T, split-K=8 partials (full-precision x) ----------------
__global__ __launch_bounds__(256) void lorad_kernel(const float* __restrict__ x,
                                                    const float* __restrict__ ld,
                                                    float* __restrict__ tr8) {
  __shared__ float Xs[128][68];
  __shared__ float Ls[32][68];
  int b = blockIdx.x;
  int t0 = (b >> 3) * 128;      // 32 token tiles
  int kbase = (b & 7) * 512;    // 8 K splits
  int tid = threadIdx.x;
  int rb = tid & 7;             // rank base: rb + {0,8,16,24}
  int tb = tid >> 3;            // token base: tb + {0,32,64,96}
  float acc[4][4];
#pragma unroll
  for (int i = 0; i < 4; ++i)
#pragma unroll
    for (int j = 0; j < 4; ++j) acc[i][j] = 0.f;

  for (int kc = 0; kc < 512; kc += 64) {
    int k0 = kbase + kc;
    __syncthreads();
#pragma unroll
    for (int s = 0; s < 8; ++s) {   // Xs: 128x64 floats = 2048 float4
      int e = tid + s * 256;
      int row = e >> 4, c4 = (e & 15) * 4;
      float4 vv = *(const float4*)(x + (size_t)(t0 + row) * IN_F + k0 + c4);
      *(float4*)&Xs[row][c4] = vv;
    }
#pragma unroll
    for (int s = 0; s < 2; ++s) {   // Ls: 32x64 floats = 512 float4
      int e = tid + s * 256;
      int row = e >> 4, c4 = (e & 15) * 4;
      float4 vv = *(const float4*)(ld + (size_t)row * IN_F + k0 + c4);
      *(float4*)&Ls[row][c4] = vv;
    }
    __syncthreads();
    for (int k4 = 0; k4 < 64; k4 += 4) {
      float4 lv[4], xv[4];
#pragma unroll
      for (int r = 0; r < 4; ++r) lv[r] = *(float4*)&Ls[rb + r * 8][k4];
#pragma unroll
      for (int mm = 0; mm < 4; ++mm) xv[mm] = *(float4*)&Xs[tb + mm * 32][k4];
#pragma unroll
      for (int mm = 0; mm < 4; ++mm)
#pragma unroll
        for (int r = 0; r < 4; ++r)
          acc[mm][r] += xv[mm].x * lv[r].x + xv[mm].y * lv[r].y +
                        xv[mm].z * lv[r].z + xv[mm].w * lv[r].w;
    }
  }
  float* dst = tr8 + (size_t)(b & 7) * NTOK * RANK;
#pragma unroll
  for (int mm = 0; mm < 4; ++mm)
#pragma unroll
    for (int r = 0; r < 4; ++r)
      dst[(size_t)(t0 + tb + mm * 32) * RANK + rb + r * 8] = acc[mm][r];
}

// ---------------- trwrite: sum split-K partials, scale by 1/ascale, append to A ----------------
__global__ __launch_bounds__(256) void trwrite_kernel(const float* __restrict__ tr8,
                                                      const float* __restrict__ ascale,
                                                      u16* __restrict__ A) {
  int idx = blockIdx.x * 256 + threadIdx.x;  // 0 .. 4096*32-1
  int t = idx >> 5, r = idx & 31;
  float s = 0.f;
#pragma unroll
  for (int k = 0; k < 8; ++k) s += tr8[(size_t)k * NTOK * RANK + idx];
  A[(size_t)t * KEXT + IN_F + r] = f2bf(s / ascale[t]);
}

// ---------------- main GEMM: C = A_ext * B_ext^T (K=4128), epilogue *ascale + bias ----------------
__global__ __launch_bounds__(256) void gemm_kernel(const u16* __restrict__ A,
                                                   const u16* __restrict__ B,
                                                   const float* __restrict__ ascale,
                                                   const float* __restrict__ bias,
                                                   float* __restrict__ out) {
  __shared__ __align__(16) u16 As[128 * 32];
  __shared__ __align__(16) u16 Bs[128 * 32];
  int bid = blockIdx.x;
  int bx = bid & 31, by = bid >> 5;
  int tm = by * 128, tn = bx * 128;
  int tid = threadIdx.x;
  int lane = tid & 63;
  int w = tid >> 6;
  int wr = w >> 1, wc = w & 1;
  int l15 = lane & 15, l4 = lane >> 4;

  f32x4 acc[4][4];
#pragma unroll
  for (int i = 0; i < 4; ++i)
#pragma unroll
    for (int j = 0; j < 4; ++j) acc[i][j] = (f32x4){0.f, 0.f, 0.f, 0.f};

  for (int ks = 0; ks < KEXT / 32; ++ks) {
    int k0 = ks * 32;
    __syncthreads();
#pragma unroll
    for (int s = 0; s < 2; ++s) {
      int id = s * 256 + tid;
      int row = id >> 2, ch = (id & 3) * 8;
      gload_lds16(A + (size_t)(tm + row) * KEXT + k0 + ch, &As[(size_t)id * 8]);
      gload_lds16(B + (size_t)(tn + row) * KEXT + k0 + ch, &Bs[(size_t)id * 8]);
    }
    __syncthreads();
    bf16x8 af[4], bfr[4];
#pragma unroll
    for (int i = 0; i < 4; ++i) {
      af[i] = *(const bf16x8*)&As[(wr * 64 + i * 16 + l15) * 32 + l4 * 8];
      bfr[i] = *(const bf16x8*)&Bs[(wc * 64 + i * 16 + l15) * 32 + l4 * 8];
    }
#pragma unroll
    for (int i = 0; i < 4; ++i)
#pragma unroll
      for (int j = 0; j < 4; ++j)
        acc[i][j] = __builtin_amdgcn_mfma_f32_16x16x32_bf16(af[i], bfr[j], acc[i][j], 0, 0, 0);
  }

#pragma unroll
  for (int i = 0; i < 4; ++i) {
#pragma unroll
    for (int j = 0; j < 4; ++j) {
      int col = tn + wc * 64 + j * 16 + l15;
      float bv = bias[col];
#pragma unroll
      for (int q = 0; q < 4; ++q) {
        int row = tm + wr * 64 + i * 16 + l4 * 4 + q;
        out[(size_t)row * OUT_F + col] = acc[i][j][q] * ascale[row] + bv;
      }
    }
  }
}

extern "C" void kernel_launch(void* const* d_in, const int* in_sizes, int n_in,
                              void* d_out, int out_size, void* d_ws, size_t ws_size,
                              hipStream_t stream) {
  const float* x = (const float*)d_in[0];
  const int* qw = (const int*)d_in[1];
  const float* wscale = (const float*)d_in[2];
  const float* ld = (const float*)d_in[3];
  const float* lu = (const float*)d_in[4];
  const float* bias = (const float*)d_in[5];
  float* out = (float*)d_out;

  char* ws = (char*)d_ws;
  const size_t szA = (size_t)NTOK * KEXT * sizeof(u16);   // 33,816,576
  const size_t szB = (size_t)OUT_F * KEXT * sizeof(u16);  // 33,816,576
  u16* Aext = (u16*)ws;
  u16* Bext = (u16*)(ws + szA);
  float* ascale = (float*)(ws + szA + szB);
  float* tr8 = (float*)(ws + szA + szB + 16384);          // 8*4096*32*4 = 4MB

  prep_kernel<<<NTOK, 256, 0, stream>>>(x, Aext, ascale);
  dequant_kernel<<<OUT_F, 256, 0, stream>>>(qw, wscale, lu, Bext);
  lorad_kernel<<<256, 256, 0, stream>>>(x, ld, tr8);
  trwrite_kernel<<<NTOK * RANK / 256, 256, 0, stream>>>(tr8, ascale, Aext);
  gemm_kernel<<<(NTOK / 128) * (OUT_F / 128), 256, 0, stream>>>(Aext, Bext, ascale, bias, out);
}

// Round 2
// 205.846 us; speedup vs baseline: 1.3028x; 1.3028x over previous
//
#include <hip/hip_runtime.h>

typedef __bf16 bf16x8 __attribute__((ext_vector_type(8)));
typedef float f32x4 __attribute__((ext_vector_type(4)));
typedef unsigned short u16;

#define IN_F 4096
#define OUT_F 4096
#define NTOK 4096
#define RANK 32
#define KEXT 4160              /* 4096 + 32 lora cols + 32 zero pad -> 65 K-tiles of 64 */
#define NT (KEXT / 64)         /* 65 */
#define ROWB ((size_t)KEXT * 2) /* row stride bytes = 8320 */

// round-to-nearest-even f32 -> bf16
__device__ __forceinline__ u16 f2bf(float f) {
  union { float f; unsigned u; } c; c.f = f;
  unsigned u = c.u;
  return (u16)((u + 0x7FFFu + ((u >> 16) & 1u)) >> 16);
}

__device__ __forceinline__ void gload_lds16(const void* g, void* l) {
  __builtin_amdgcn_global_load_lds((const __attribute__((address_space(1))) void*)g,
                                   (__attribute__((address_space(3))) void*)l,
                                   16, 0, 0);
}

// ---------------- prep: per-token amax -> ascale, write bf16 int codes + zero pad ----------------
__global__ __launch_bounds__(256) void prep_kernel(const float* __restrict__ x,
                                                   u16* __restrict__ A,
                                                   float* __restrict__ ascale) {
  int t = blockIdx.x;
  int tid = threadIdx.x;
  const float4* xr = (const float4*)(x + (size_t)t * IN_F);
  float4 v[4];
  float m = 0.f;
#pragma unroll
  for (int i = 0; i < 4; ++i) {
    v[i] = xr[tid + i * 256];
    m = fmaxf(m, fmaxf(fmaxf(fabsf(v[i].x), fabsf(v[i].y)),
                       fmaxf(fabsf(v[i].z), fabsf(v[i].w))));
  }
#pragma unroll
  for (int off = 32; off > 0; off >>= 1) m = fmaxf(m, __shfl_xor(m, off));
  __shared__ float wmax[4];
  if ((tid & 63) == 0) wmax[tid >> 6] = m;
  __syncthreads();
  m = fmaxf(fmaxf(wmax[0], wmax[1]), fmaxf(wmax[2], wmax[3]));
  float as = fmaxf(m, 1e-6f) / 7.f;
  float inv = 1.f / as;
  if (tid == 0) ascale[t] = as;
  u16* Ar = A + (size_t)t * KEXT;
#pragma unroll
  for (int i = 0; i < 4; ++i) {
    float q0 = fminf(fmaxf(rintf(v[i].x * inv), -8.f), 7.f);
    float q1 = fminf(fmaxf(rintf(v[i].y * inv), -8.f), 7.f);
    float q2 = fminf(fmaxf(rintf(v[i].z * inv), -8.f), 7.f);
    float q3 = fminf(fmaxf(rintf(v[i].w * inv), -8.f), 7.f);
    ushort4 u;
    u.x = f2bf(q0); u.y = f2bf(q1); u.z = f2bf(q2); u.w = f2bf(q3);
    *(ushort4*)(Ar + (size_t)(tid + i * 256) * 4) = u;
  }
  if (tid < 8) {  // zero pad cols 4128..4159
    ushort4 z; z.x = z.y = z.z = z.w = 0;
    *(ushort4*)(Ar + IN_F + 32 + tid * 4) = z;
  }
}

// ---------------- dequant: int4 codes * group scale -> bf16, append lora_up + zero pad ----------------
__global__ __launch_bounds__(256) void dequant_kernel(const int* __restrict__ qw,
                                                      const float* __restrict__ wscale,
                                                      const float* __restrict__ lu,
                                                      u16* __restrict__ B) {
  int o = blockIdx.x;
  int tid = threadIdx.x;
  const int4* qr = (const int4*)(qw + (size_t)o * IN_F);
  const float* sr = wscale + (size_t)o * (IN_F / 64);
  u16* Br = B + (size_t)o * KEXT;
#pragma unroll
  for (int s = 0; s < 4; ++s) {
    int e = tid + s * 256;
    int4 q = qr[e];
    float sc = sr[e >> 4];
    ushort4 u;
    u.x = f2bf((float)q.x * sc);
    u.y = f2bf((float)q.y * sc);
    u.z = f2bf((float)q.z * sc);
    u.w = f2bf((float)q.w * sc);
    *(ushort4*)(Br + (size_t)4 * e) = u;
  }
  if (tid < RANK) Br[IN_F + tid] = f2bf(lu[(size_t)o * RANK + tid]);
  if (tid < 8) {
    ushort4 z; z.x = z.y = z.z = z.w = 0;
    *(ushort4*)(Br + IN_F + 32 + tid * 4) = z;
  }
}

// ---------------- lorad: tr = x @ ld^T, split-K=8 partials ----------------
__global__ __launch_bounds__(256) void lorad_kernel(const float* __restrict__ x,
                                                    const float* __restrict__ ld,
                                                    float* __restrict__ tr8) {
  __shared__ float Xs[128][68];
  __shared__ float Ls[32][68];
  int b = blockIdx.x;
  int t0 = (b >> 3) * 128;
  int kbase = (b & 7) * 512;
  int tid = threadIdx.x;
  int rb = tid & 7;
  int tb = tid >> 3;
  float acc[4][4];
#pragma unroll
  for (int i = 0; i < 4; ++i)
#pragma unroll
    for (int j = 0; j < 4; ++j) acc[i][j] = 0.f;

  for (int kc = 0; kc < 512; kc += 64) {
    int k0 = kbase + kc;
    __syncthreads();
#pragma unroll
    for (int s = 0; s < 8; ++s) {
      int e = tid + s * 256;
      int row = e >> 4, c4 = (e & 15) * 4;
      float4 vv = *(const float4*)(x + (size_t)(t0 + row) * IN_F + k0 + c4);
      *(float4*)&Xs[row][c4] = vv;
    }
#pragma unroll
    for (int s = 0; s < 2; ++s) {
      int e = tid + s * 256;
      int row = e >> 4, c4 = (e & 15) * 4;
      float4 vv = *(const float4*)(ld + (size_t)row * IN_F + k0 + c4);
      *(float4*)&Ls[row][c4] = vv;
    }
    __syncthreads();
    for (int k4 = 0; k4 < 64; k4 += 4) {
      float4 lv[4], xv[4];
#pragma unroll
      for (int r = 0; r < 4; ++r) lv[r] = *(float4*)&Ls[rb + r * 8][k4];
#pragma unroll
      for (int mm = 0; mm < 4; ++mm) xv[mm] = *(float4*)&Xs[tb + mm * 32][k4];
#pragma unroll
      for (int mm = 0; mm < 4; ++mm)
#pragma unroll
        for (int r = 0; r < 4; ++r)
          acc[mm][r] += xv[mm].x * lv[r].x + xv[mm].y * lv[r].y +
                        xv[mm].z * lv[r].z + xv[mm].w * lv[r].w;
    }
  }
  float* dst = tr8 + (size_t)(b & 7) * NTOK * RANK;
#pragma unroll
  for (int mm = 0; mm < 4; ++mm)
#pragma unroll
    for (int r = 0; r < 4; ++r)
      dst[(size_t)(t0 + tb + mm * 32) * RANK + rb + r * 8] = acc[mm][r];
}

// ---------------- trwrite ----------------
__global__ __launch_bounds__(256) void trwrite_kernel(const float* __restrict__ tr8,
                                                      const float* __restrict__ ascale,
                                                      u16* __restrict__ A) {
  int idx = blockIdx.x * 256 + threadIdx.x;
  int t = idx >> 5, r = idx & 31;
  float s = 0.f;
#pragma unroll
  for (int k = 0; k < 8; ++k) s += tr8[(size_t)k * NTOK * RANK + idx];
  A[(size_t)t * KEXT + IN_F + r] = f2bf(s / ascale[t]);
}

// ---------------- main GEMM: 256x256 tile, BK=64, 8-wave, 8-phase, st_16x32 swizzle ----------------
// LDS map (bytes): A buf c at c*32768 (half0 16KB, half1 16KB); B buf c at 65536 + c*32768.
// Swizzle: within-buffer byte addr b -> b ^ (((b>>9)&1)<<5). Applied on ds_read side;
// staging pre-swizzles the GLOBAL column so the linear gload_lds dest holds swizzled content.

__device__ __forceinline__ void stage_tile(const char* g, char* ldst, int tid) {
#pragma unroll
  for (int h = 0; h < 4; ++h)
    gload_lds16(g + (size_t)h * (64 * ROWB), ldst + h * 8192 + tid * 16);
}

#define BARRIER() do { asm volatile("s_barrier" ::: "memory"); __builtin_amdgcn_sched_barrier(0); } while (0)

__global__ __launch_bounds__(512, 2) void gemm_kernel(const u16* __restrict__ A,
                                                      const u16* __restrict__ B,
                                                      const float* __restrict__ ascale,
                                                      const float* __restrict__ bias,
                                                      float* __restrict__ out) {
  __shared__ __align__(16) char smem[131072];
  int b = blockIdx.x;
  int swz = (b & 7) * 32 + (b >> 3);     // 256 blocks, 8 XCDs -> bijective
  int by = swz >> 4, bx = swz & 15;
  int tm = by * 256, tn = bx * 256;
  int tid = threadIdx.x;
  int lane = tid & 63, wid = tid >> 6;
  int wr = wid >> 2, wc = wid & 3;       // 2x4 wave grid; wave owns 128x64 of C
  int l15 = lane & 15, l4 = lane >> 4;
  int xorb = ((l15 >> 2) & 1) << 5;      // bit9 of row*128 = (l15>>2)&1 -> constant per lane
  int a_off = (wr * 16384 + l15 * 128 + l4 * 16) ^ xorb;
  int b_off = ((wc >> 1) * 16384 + (wc & 1) * 8192 + l15 * 128 + l4 * 16) ^ xorb;

  // staging: thread loads 4x16B per matrix half-pair; pre-swizzled global column
  int r0 = tid >> 3;
  int cb = ((tid * 16) & 127) ^ (((tid >> 5) & 1) << 5);
  const char* ag = (const char*)A + (size_t)(tm + r0) * ROWB + cb;
  const char* bg = (const char*)B + (size_t)(tn + r0) * ROWB + cb;

  f32x4 acc[8][4];
#pragma unroll
  for (int i = 0; i < 8; ++i)
#pragma unroll
    for (int j = 0; j < 4; ++j) acc[i][j] = (f32x4){0.f, 0.f, 0.f, 0.f};

  // prologue: stage tiles 0 (buf0) and 1 (buf1)
  stage_tile(ag, smem, tid);
  stage_tile(bg, smem + 65536, tid);
  stage_tile(ag + 128, smem + 32768, tid);
  stage_tile(bg + 128, smem + 65536 + 32768, tid);
  asm volatile("s_waitcnt vmcnt(8)" ::: "memory");  // tile 0 landed; tile 1 in flight
  BARRIER();

  const char* apf = ag + 256;  // tile t+2 source (t=0)
  const char* bpf = bg + 256;
  bf16x8 af[8][2], bf[2][2];

  for (int t = 0; t < NT; ++t) {
    int c = t & 1;
    int ao = c * 32768 + a_off;
    int bo = 65536 + c * 32768 + b_off;
    bool pf = (t + 2) < NT;

    // ---- P1: read A m0-3 (8), B n0-1 (4) ----
#pragma unroll
    for (int i = 0; i < 4; ++i) {
      af[i][0] = *(const bf16x8*)(smem + ao + i * 2048);
      af[i][1] = *(const bf16x8*)(smem + ao + i * 2048 + 64);
    }
#pragma unroll
    for (int j = 0; j < 2; ++j) {
      bf[j][0] = *(const bf16x8*)(smem + bo + j * 2048);
      bf[j][1] = *(const bf16x8*)(smem + bo + j * 2048 + 64);
    }
    BARRIER();
    __builtin_amdgcn_s_setprio(1);
#pragma unroll
    for (int i = 0; i < 4; ++i)
#pragma unroll
      for (int j = 0; j < 2; ++j) {
        acc[i][j] = __builtin_amdgcn_mfma_f32_16x16x32_bf16(af[i][0], bf[j][0], acc[i][j], 0, 0, 0);
        acc[i][j] = __builtin_amdgcn_mfma_f32_16x16x32_bf16(af[i][1], bf[j][1], acc[i][j], 0, 0, 0);
      }
    __builtin_amdgcn_s_setprio(0);
    __builtin_amdgcn_sched_barrier(0);
    BARRIER();

    // ---- P2: read A m4-7 (8) ----
#pragma unroll
    for (int i = 4; i < 8; ++i) {
      af[i][0] = *(const bf16x8*)(smem + ao + i * 2048);
      af[i][1] = *(const bf16x8*)(smem + ao + i * 2048 + 64);
    }
    BARRIER();
    __builtin_amdgcn_s_setprio(1);
#pragma unroll
    for (int i = 4; i < 8; ++i)
#pragma unroll
      for (int j = 0; j < 2; ++j) {
        acc[i][j] = __builtin_amdgcn_mfma_f32_16x16x32_bf16(af[i][0], bf[j][0], acc[i][j], 0, 0, 0);
        acc[i][j] = __builtin_amdgcn_mfma_f32_16x16x32_bf16(af[i][1], bf[j][1], acc[i][j], 0, 0, 0);
      }
    __builtin_amdgcn_s_setprio(0);
    __builtin_amdgcn_sched_barrier(0);
    BARRIER();

    // ---- P3: read B n2-3 (4); stage A of tile t+2 into buf c (A reads done at P2 barrier) ----
#pragma unroll
    for (int j = 0; j < 2; ++j) {
      bf[j][0] = *(const bf16x8*)(smem + bo + (j + 2) * 2048);
      bf[j][1] = *(const bf16x8*)(smem + bo + (j + 2) * 2048 + 64);
    }
    if (pf) stage_tile(apf, smem + c * 32768, tid);
    BARRIER();
    __builtin_amdgcn_s_setprio(1);
#pragma unroll
    for (int i = 0; i < 4; ++i)
#pragma unroll
      for (int j = 0; j < 2; ++j) {
        acc[i][j + 2] = __builtin_amdgcn_mfma_f32_16x16x32_bf16(af[i][0], bf[j][0], acc[i][j + 2], 0, 0, 0);
        acc[i][j + 2] = __builtin_amdgcn_mfma_f32_16x16x32_bf16(af[i][1], bf[j][1], acc[i][j + 2], 0, 0, 0);
      }
    __builtin_amdgcn_s_setprio(0);
    __builtin_amdgcn_sched_barrier(0);
    BARRIER();

    // ---- P4: stage B of tile t+2 into buf c (B reads done at P3 barrier); counted vmcnt ----
    if (pf) {
      stage_tile(bpf, smem + 65536 + c * 32768, tid);
      asm volatile("s_waitcnt vmcnt(8)" ::: "memory");  // tile t+1 landed; t+2 (8 loads) in flight
    } else if (t == NT - 2) {
      asm volatile("s_waitcnt vmcnt(0)" ::: "memory");  // epilogue drain
    }
    BARRIER();
    __builtin_amdgcn_s_setprio(1);
#pragma unroll
    for (int i = 4; i < 8; ++i)
#pragma unroll
      for (int j = 0; j < 2; ++j) {
        acc[i][j + 2] = __builtin_amdgcn_mfma_f32_16x16x32_bf16(af[i][0], bf[j][0], acc[i][j + 2], 0, 0, 0);
        acc[i][j + 2] = __builtin_amdgcn_mfma_f32_16x16x32_bf16(af[i][1], bf[j][1], acc[i][j + 2], 0, 0, 0);
      }
    __builtin_amdgcn_s_setprio(0);
    __builtin_amdgcn_sched_barrier(0);
    BARRIER();

    apf += 128;
    bpf += 128;
  }

  // ---- epilogue: C = acc * ascale[row] + bias[col] ----
#pragma unroll
  for (int i = 0; i < 8; ++i) {
    int rowb = tm + wr * 128 + i * 16 + l4 * 4;
#pragma unroll
    for (int j = 0; j < 4; ++j) {
      int col = tn + wc * 64 + j * 16 + l15;
      float bv = bias[col];
#pragma unroll
      for (int q = 0; q < 4; ++q)
        out[(size_t)(rowb + q) * OUT_F + col] = acc[i][j][q] * ascale[rowb + q] + bv;
    }
  }
}

extern "C" void kernel_launch(void* const* d_in, const int* in_sizes, int n_in,
                              void* d_out, int out_size, void* d_ws, size_t ws_size,
                              hipStream_t stream) {
  const float* x = (const float*)d_in[0];
  const int* qw = (const int*)d_in[1];
  const float* wscale = (const float*)d_in[2];
  const float* ld = (const float*)d_in[3];
  const float* lu = (const float*)d_in[4];
  const float* bias = (const float*)d_in[5];
  float* out = (float*)d_out;

  char* ws = (char*)d_ws;
  const size_t szA = (size_t)NTOK * KEXT * sizeof(u16);
  const size_t szB = (size_t)OUT_F * KEXT * sizeof(u16);
  u16* Aext = (u16*)ws;
  u16* Bext = (u16*)(ws + szA);
  float* ascale = (float*)(ws + szA + szB);
  float* tr8 = (float*)(ws + szA + szB + 16384);

  prep_kernel<<<NTOK, 256, 0, stream>>>(x, Aext, ascale);
  dequant_kernel<<<OUT_F, 256, 0, stream>>>(qw, wscale, lu, Bext);
  lorad_kernel<<<256, 256, 0, stream>>>(x, ld, tr8);
  trwrite_kernel<<<NTOK * RANK / 256, 256, 0, stream>>>(tr8, ascale, Aext);
  gemm_kernel<<<(NTOK / 256) * (OUT_F / 256), 512, 0, stream>>>(Aext, Bext, ascale, bias, out);
}

// Round 3
// 193.962 us; speedup vs baseline: 1.3826x; 1.0613x over previous
//
#include <hip/hip_runtime.h>

typedef __bf16 bf16x8 __attribute__((ext_vector_type(8)));
typedef float f32x4 __attribute__((ext_vector_type(4)));
typedef unsigned short u16;

#define IN_F 4096
#define OUT_F 4096
#define NTOK 4096
#define RANK 32
#define KEXT 4160              /* 4096 + 32 lora cols + 32 zero pad -> 65 K-tiles of 64 */
#define NT (KEXT / 64)         /* 65 */
#define ROWB ((size_t)KEXT * 2) /* row stride bytes = 8320 */

// round-to-nearest-even f32 -> bf16
__device__ __forceinline__ u16 f2bf(float f) {
  union { float f; unsigned u; } c; c.f = f;
  unsigned u = c.u;
  return (u16)((u + 0x7FFFu + ((u >> 16) & 1u)) >> 16);
}

__device__ __forceinline__ void gload_lds16(const void* g, void* l) {
  __builtin_amdgcn_global_load_lds((const __attribute__((address_space(1))) void*)g,
                                   (__attribute__((address_space(3))) void*)l,
                                   16, 0, 0);
}

// ---------------- prep: per-token amax -> ascale, write bf16 int codes + zero pad ----------------
__global__ __launch_bounds__(256) void prep_kernel(const float* __restrict__ x,
                                                   u16* __restrict__ A,
                                                   float* __restrict__ ascale) {
  int t = blockIdx.x;
  int tid = threadIdx.x;
  const float4* xr = (const float4*)(x + (size_t)t * IN_F);
  float4 v[4];
  float m = 0.f;
#pragma unroll
  for (int i = 0; i < 4; ++i) {
    v[i] = xr[tid + i * 256];
    m = fmaxf(m, fmaxf(fmaxf(fabsf(v[i].x), fabsf(v[i].y)),
                       fmaxf(fabsf(v[i].z), fabsf(v[i].w))));
  }
#pragma unroll
  for (int off = 32; off > 0; off >>= 1) m = fmaxf(m, __shfl_xor(m, off));
  __shared__ float wmax[4];
  if ((tid & 63) == 0) wmax[tid >> 6] = m;
  __syncthreads();
  m = fmaxf(fmaxf(wmax[0], wmax[1]), fmaxf(wmax[2], wmax[3]));
  float as = fmaxf(m, 1e-6f) / 7.f;
  float inv = 1.f / as;
  if (tid == 0) ascale[t] = as;
  u16* Ar = A + (size_t)t * KEXT;
#pragma unroll
  for (int i = 0; i < 4; ++i) {
    float q0 = fminf(fmaxf(rintf(v[i].x * inv), -8.f), 7.f);
    float q1 = fminf(fmaxf(rintf(v[i].y * inv), -8.f), 7.f);
    float q2 = fminf(fmaxf(rintf(v[i].z * inv), -8.f), 7.f);
    float q3 = fminf(fmaxf(rintf(v[i].w * inv), -8.f), 7.f);
    ushort4 u;
    u.x = f2bf(q0); u.y = f2bf(q1); u.z = f2bf(q2); u.w = f2bf(q3);
    *(ushort4*)(Ar + (size_t)(tid + i * 256) * 4) = u;
  }
  if (tid < 8) {  // zero pad cols 4128..4159
    ushort4 z; z.x = z.y = z.z = z.w = 0;
    *(ushort4*)(Ar + IN_F + 32 + tid * 4) = z;
  }
}

// ---------------- dequant: int4 codes * group scale -> bf16, append lora_up + zero pad ----------------
__global__ __launch_bounds__(256) void dequant_kernel(const int* __restrict__ qw,
                                                      const float* __restrict__ wscale,
                                                      const float* __restrict__ lu,
                                                      u16* __restrict__ B) {
  int o = blockIdx.x;
  int tid = threadIdx.x;
  const int4* qr = (const int4*)(qw + (size_t)o * IN_F);
  const float* sr = wscale + (size_t)o * (IN_F / 64);
  u16* Br = B + (size_t)o * KEXT;
#pragma unroll
  for (int s = 0; s < 4; ++s) {
    int e = tid + s * 256;
    int4 q = qr[e];
    float sc = sr[e >> 4];
    ushort4 u;
    u.x = f2bf((float)q.x * sc);
    u.y = f2bf((float)q.y * sc);
    u.z = f2bf((float)q.z * sc);
    u.w = f2bf((float)q.w * sc);
    *(ushort4*)(Br + (size_t)4 * e) = u;
  }
  if (tid < RANK) Br[IN_F + tid] = f2bf(lu[(size_t)o * RANK + tid]);
  if (tid < 8) {
    ushort4 z; z.x = z.y = z.z = z.w = 0;
    *(ushort4*)(Br + IN_F + 32 + tid * 4) = z;
  }
}

// ---------------- lorad: tr = x @ ld^T, split-K=8 partials ----------------
__global__ __launch_bounds__(256) void lorad_kernel(const float* __restrict__ x,
                                                    const float* __restrict__ ld,
                                                    float* __restrict__ tr8) {
  __shared__ float Xs[128][68];
  __shared__ float Ls[32][68];
  int b = blockIdx.x;
  int t0 = (b >> 3) * 128;
  int kbase = (b & 7) * 512;
  int tid = threadIdx.x;
  int rb = tid & 7;
  int tb = tid >> 3;
  float acc[4][4];
#pragma unroll
  for (int i = 0; i < 4; ++i)
#pragma unroll
    for (int j = 0; j < 4; ++j) acc[i][j] = 0.f;

  for (int kc = 0; kc < 512; kc += 64) {
    int k0 = kbase + kc;
    __syncthreads();
#pragma unroll
    for (int s = 0; s < 8; ++s) {
      int e = tid + s * 256;
      int row = e >> 4, c4 = (e & 15) * 4;
      float4 vv = *(const float4*)(x + (size_t)(t0 + row) * IN_F + k0 + c4);
      *(float4*)&Xs[row][c4] = vv;
    }
#pragma unroll
    for (int s = 0; s < 2; ++s) {
      int e = tid + s * 256;
      int row = e >> 4, c4 = (e & 15) * 4;
      float4 vv = *(const float4*)(ld + (size_t)row * IN_F + k0 + c4);
      *(float4*)&Ls[row][c4] = vv;
    }
    __syncthreads();
    for (int k4 = 0; k4 < 64; k4 += 4) {
      float4 lv[4], xv[4];
#pragma unroll
      for (int r = 0; r < 4; ++r) lv[r] = *(float4*)&Ls[rb + r * 8][k4];
#pragma unroll
      for (int mm = 0; mm < 4; ++mm) xv[mm] = *(float4*)&Xs[tb + mm * 32][k4];
#pragma unroll
      for (int mm = 0; mm < 4; ++mm)
#pragma unroll
        for (int r = 0; r < 4; ++r)
          acc[mm][r] += xv[mm].x * lv[r].x + xv[mm].y * lv[r].y +
                        xv[mm].z * lv[r].z + xv[mm].w * lv[r].w;
    }
  }
  float* dst = tr8 + (size_t)(b & 7) * NTOK * RANK;
#pragma unroll
  for (int mm = 0; mm < 4; ++mm)
#pragma unroll
    for (int r = 0; r < 4; ++r)
      dst[(size_t)(t0 + tb + mm * 32) * RANK + rb + r * 8] = acc[mm][r];
}

// ---------------- trwrite ----------------
__global__ __launch_bounds__(256) void trwrite_kernel(const float* __restrict__ tr8,
                                                      const float* __restrict__ ascale,
                                                      u16* __restrict__ A) {
  int idx = blockIdx.x * 256 + threadIdx.x;
  int t = idx >> 5, r = idx & 31;
  float s = 0.f;
#pragma unroll
  for (int k = 0; k < 8; ++k) s += tr8[(size_t)k * NTOK * RANK + idx];
  A[(size_t)t * KEXT + IN_F + r] = f2bf(s / ascale[t]);
}

// ---------------- main GEMM: 256x256 tile, BK=64, 8-wave, 8-phase ----------------
// LDS map (bytes): A buf c at c*32768; B buf c at 65536 + c*32768. Each buffer:
// 256 rows x 128 bytes (64 bf16 K-cols). Swizzle (T2 recipe): within a row,
// 16B chunk u holds global chunk u ^ (row & 7). Staging keeps gload_lds dest
// LINEAR and pre-swizzles the GLOBAL source chunk (involution); ds_read applies
// the same XOR. Bank-group = 4*(l4 ^ (l15&7)) -> 2 lanes/bank = conflict-free.

__device__ __forceinline__ void stage_tile(const char* g, char* ldst, int tid) {
#pragma unroll
  for (int h = 0; h < 4; ++h)
    gload_lds16(g + (size_t)h * (64 * ROWB), ldst + h * 8192 + tid * 16);
}

#define BARRIER() do { asm volatile("s_barrier" ::: "memory"); __builtin_amdgcn_sched_barrier(0); } while (0)

__global__ __launch_bounds__(512, 2) void gemm_kernel(const u16* __restrict__ A,
                                                      const u16* __restrict__ B,
                                                      const float* __restrict__ ascale,
                                                      const float* __restrict__ bias,
                                                      float* __restrict__ out) {
  __shared__ __align__(16) char smem[131072];
  int b = blockIdx.x;
  int swz = (b & 7) * 32 + (b >> 3);     // 256 blocks, 8 XCDs -> bijective
  int by = swz >> 4, bx = swz & 15;
  int tm = by * 256, tn = bx * 256;
  int tid = threadIdx.x;
  int lane = tid & 63, wid = tid >> 6;
  int wr = wid >> 2, wc = wid & 3;       // 2x4 wave grid; wave owns 128x64 of C
  int l15 = lane & 15, l4 = lane >> 4;
  int xorb = (l15 & 7) << 4;             // row&7 -> 16B-chunk XOR (bits 4-6)
  int colx0 = (l4 * 16) ^ xorb;          // K elements l4*8 .. +7
  int colx1 = (l4 * 16 + 64) ^ xorb;     // K elements 32+l4*8 .. +7
  int a_base = wr * 16384 + l15 * 128;   // row = wr*128 + i*16 + l15
  int b_base = wc * 8192 + l15 * 128;    // row = wc*64 + j*16 + l15

  // staging: thread tid writes LDS bytes [h*8192 + tid*16); source column chunk
  // is (tid&7) ^ (row&7), row = tid>>3 within the 64-row h-block.
  int r0 = tid >> 3;
  int cb = (((tid & 7) ^ ((tid >> 3) & 7)) << 4);
  const char* ag = (const char*)A + (size_t)(tm + r0) * ROWB + cb;
  const char* bg = (const char*)B + (size_t)(tn + r0) * ROWB + cb;

  f32x4 acc[8][4];
#pragma unroll
  for (int i = 0; i < 8; ++i)
#pragma unroll
    for (int j = 0; j < 4; ++j) acc[i][j] = (f32x4){0.f, 0.f, 0.f, 0.f};

  // prologue: stage tiles 0 (buf0) and 1 (buf1)
  stage_tile(ag, smem, tid);
  stage_tile(bg, smem + 65536, tid);
  stage_tile(ag + 128, smem + 32768, tid);
  stage_tile(bg + 128, smem + 65536 + 32768, tid);
  asm volatile("s_waitcnt vmcnt(8)" ::: "memory");  // tile 0 landed; tile 1 (8 instrs) in flight
  BARRIER();

  const char* apf = ag + 256;  // tile t+2 source (t=0)
  const char* bpf = bg + 256;
  bf16x8 af[8][2], bf[2][2];

  for (int t = 0; t < NT; ++t) {
    int c = t & 1;
    int ao = c * 32768 + a_base;
    int bo = 65536 + c * 32768 + b_base;
    bool pf = (t + 2) < NT;

    // ---- P1: read A m0-3 (8), B n0-1 (4) ----
#pragma unroll
    for (int i = 0; i < 4; ++i) {
      af[i][0] = *(const bf16x8*)(smem + ao + i * 2048 + colx0);
      af[i][1] = *(const bf16x8*)(smem + ao + i * 2048 + colx1);
    }
#pragma unroll
    for (int j = 0; j < 2; ++j) {
      bf[j][0] = *(const bf16x8*)(smem + bo + j * 2048 + colx0);
      bf[j][1] = *(const bf16x8*)(smem + bo + j * 2048 + colx1);
    }
    BARRIER();
    __builtin_amdgcn_s_setprio(1);
#pragma unroll
    for (int i = 0; i < 4; ++i)
#pragma unroll
      for (int j = 0; j < 2; ++j) {
        acc[i][j] = __builtin_amdgcn_mfma_f32_16x16x32_bf16(af[i][0], bf[j][0], acc[i][j], 0, 0, 0);
        acc[i][j] = __builtin_amdgcn_mfma_f32_16x16x32_bf16(af[i][1], bf[j][1], acc[i][j], 0, 0, 0);
      }
    __builtin_amdgcn_s_setprio(0);
    __builtin_amdgcn_sched_barrier(0);
    BARRIER();

    // ---- P2: read A m4-7 (8) ----
#pragma unroll
    for (int i = 4; i < 8; ++i) {
      af[i][0] = *(const bf16x8*)(smem + ao + i * 2048 + colx0);
      af[i][1] = *(const bf16x8*)(smem + ao + i * 2048 + colx1);
    }
    BARRIER();
    __builtin_amdgcn_s_setprio(1);
#pragma unroll
    for (int i = 4; i < 8; ++i)
#pragma unroll
      for (int j = 0; j < 2; ++j) {
        acc[i][j] = __builtin_amdgcn_mfma_f32_16x16x32_bf16(af[i][0], bf[j][0], acc[i][j], 0, 0, 0);
        acc[i][j] = __builtin_amdgcn_mfma_f32_16x16x32_bf16(af[i][1], bf[j][1], acc[i][j], 0, 0, 0);
      }
    __builtin_amdgcn_s_setprio(0);
    __builtin_amdgcn_sched_barrier(0);
    BARRIER();

    // ---- P3: read B n2-3 (4); stage A of tile t+2 into buf c (A reads done at P2 barrier) ----
#pragma unroll
    for (int j = 0; j < 2; ++j) {
      bf[j][0] = *(const bf16x8*)(smem + bo + (j + 2) * 2048 + colx0);
      bf[j][1] = *(const bf16x8*)(smem + bo + (j + 2) * 2048 + colx1);
    }
    if (pf) stage_tile(apf, smem + c * 32768, tid);
    BARRIER();
    __builtin_amdgcn_s_setprio(1);
#pragma unroll
    for (int i = 0; i < 4; ++i)
#pragma unroll
      for (int j = 0; j < 2; ++j) {
        acc[i][j + 2] = __builtin_amdgcn_mfma_f32_16x16x32_bf16(af[i][0], bf[j][0], acc[i][j + 2], 0, 0, 0);
        acc[i][j + 2] = __builtin_amdgcn_mfma_f32_16x16x32_bf16(af[i][1], bf[j][1], acc[i][j + 2], 0, 0, 0);
      }
    __builtin_amdgcn_s_setprio(0);
    __builtin_amdgcn_sched_barrier(0);
    BARRIER();

    // ---- P4: stage B of tile t+2 into buf c (B reads done at P3 barrier); counted vmcnt ----
    if (pf) {
      stage_tile(bpf, smem + 65536 + c * 32768, tid);
      asm volatile("s_waitcnt vmcnt(8)" ::: "memory");  // t+1 landed; t+2 (8 instrs) in flight
    } else if (t == NT - 2) {
      asm volatile("s_waitcnt vmcnt(0)" ::: "memory");  // epilogue drain
    }
    BARRIER();
    __builtin_amdgcn_s_setprio(1);
#pragma unroll
    for (int i = 4; i < 8; ++i)
#pragma unroll
      for (int j = 0; j < 2; ++j) {
        acc[i][j + 2] = __builtin_amdgcn_mfma_f32_16x16x32_bf16(af[i][0], bf[j][0], acc[i][j + 2], 0, 0, 0);
        acc[i][j + 2] = __builtin_amdgcn_mfma_f32_16x16x32_bf16(af[i][1], bf[j][1], acc[i][j + 2], 0, 0, 0);
      }
    __builtin_amdgcn_s_setprio(0);
    __builtin_amdgcn_sched_barrier(0);
    BARRIER();

    apf += 128;
    bpf += 128;
  }

  // ---- epilogue: C = acc * ascale[row] + bias[col] ----
#pragma unroll
  for (int i = 0; i < 8; ++i) {
    int rowb = tm + wr * 128 + i * 16 + l4 * 4;
#pragma unroll
    for (int j = 0; j < 4; ++j) {
      int col = tn + wc * 64 + j * 16 + l15;
      float bv = bias[col];
#pragma unroll
      for (int q = 0; q < 4; ++q)
        out[(size_t)(rowb + q) * OUT_F + col] = acc[i][j][q] * ascale[rowb + q] + bv;
    }
  }
}

extern "C" void kernel_launch(void* const* d_in, const int* in_sizes, int n_in,
                              void* d_out, int out_size, void* d_ws, size_t ws_size,
                              hipStream_t stream) {
  const float* x = (const float*)d_in[0];
  const int* qw = (const int*)d_in[1];
  const float* wscale = (const float*)d_in[2];
  const float* ld = (const float*)d_in[3];
  const float* lu = (const float*)d_in[4];
  const float* bias = (const float*)d_in[5];
  float* out = (float*)d_out;

  char* ws = (char*)d_ws;
  const size_t szA = (size_t)NTOK * KEXT * sizeof(u16);
  const size_t szB = (size_t)OUT_F * KEXT * sizeof(u16);
  u16* Aext = (u16*)ws;
  u16* Bext = (u16*)(ws + szA);
  float* ascale = (float*)(ws + szA + szB);
  float* tr8 = (float*)(ws + szA + szB + 16384);

  prep_kernel<<<NTOK, 256, 0, stream>>>(x, Aext, ascale);
  dequant_kernel<<<OUT_F, 256, 0, stream>>>(qw, wscale, lu, Bext);
  lorad_kernel<<<256, 256, 0, stream>>>(x, ld, tr8);
  trwrite_kernel<<<NTOK * RANK / 256, 256, 0, stream>>>(tr8, ascale, Aext);
  gemm_kernel<<<(NTOK / 256) * (OUT_F / 256), 512, 0, stream>>>(Aext, Bext, ascale, bias, out);
}

// Round 4
// 180.128 us; speedup vs baseline: 1.4888x; 1.0768x over previous
//
#include <hip/hip_runtime.h>

typedef __bf16 bf16x8 __attribute__((ext_vector_type(8)));
typedef float f32x4 __attribute__((ext_vector_type(4)));
typedef unsigned short u16;

#define IN_F 4096
#define OUT_F 4096
#define NTOK 4096
#define RANK 32
#define KEXT 4160              /* 4096 + 32 lora cols + 32 zero pad -> 65 K-tiles of 64 */
#define NT (KEXT / 64)         /* 65 */
#define ROWB ((size_t)KEXT * 2) /* row stride bytes = 8320 */

// round-to-nearest-even f32 -> bf16
__device__ __forceinline__ u16 f2bf(float f) {
  union { float f; unsigned u; } c; c.f = f;
  unsigned u = c.u;
  return (u16)((u + 0x7FFFu + ((u >> 16) & 1u)) >> 16);
}

__device__ __forceinline__ void gload_lds16(const void* g, void* l) {
  __builtin_amdgcn_global_load_lds((const __attribute__((address_space(1))) void*)g,
                                   (__attribute__((address_space(3))) void*)l,
                                   16, 0, 0);
}

// ---------------- prep: per-token amax -> ascale, write bf16 int codes + zero pad ----------------
__global__ __launch_bounds__(256) void prep_kernel(const float* __restrict__ x,
                                                   u16* __restrict__ A,
                                                   float* __restrict__ ascale) {
  int t = blockIdx.x;
  int tid = threadIdx.x;
  const float4* xr = (const float4*)(x + (size_t)t * IN_F);
  float4 v[4];
  float m = 0.f;
#pragma unroll
  for (int i = 0; i < 4; ++i) {
    v[i] = xr[tid + i * 256];
    m = fmaxf(m, fmaxf(fmaxf(fabsf(v[i].x), fabsf(v[i].y)),
                       fmaxf(fabsf(v[i].z), fabsf(v[i].w))));
  }
#pragma unroll
  for (int off = 32; off > 0; off >>= 1) m = fmaxf(m, __shfl_xor(m, off));
  __shared__ float wmax[4];
  if ((tid & 63) == 0) wmax[tid >> 6] = m;
  __syncthreads();
  m = fmaxf(fmaxf(wmax[0], wmax[1]), fmaxf(wmax[2], wmax[3]));
  float as = fmaxf(m, 1e-6f) / 7.f;
  float inv = 1.f / as;
  if (tid == 0) ascale[t] = as;
  u16* Ar = A + (size_t)t * KEXT;
#pragma unroll
  for (int i = 0; i < 4; ++i) {
    float q0 = fminf(fmaxf(rintf(v[i].x * inv), -8.f), 7.f);
    float q1 = fminf(fmaxf(rintf(v[i].y * inv), -8.f), 7.f);
    float q2 = fminf(fmaxf(rintf(v[i].z * inv), -8.f), 7.f);
    float q3 = fminf(fmaxf(rintf(v[i].w * inv), -8.f), 7.f);
    ushort4 u;
    u.x = f2bf(q0); u.y = f2bf(q1); u.z = f2bf(q2); u.w = f2bf(q3);
    *(ushort4*)(Ar + (size_t)(tid + i * 256) * 4) = u;
  }
  if (tid < 8) {  // zero pad cols 4128..4159
    ushort4 z; z.x = z.y = z.z = z.w = 0;
    *(ushort4*)(Ar + IN_F + 32 + tid * 4) = z;
  }
}

// ---------------- dequant: int4 codes * group scale -> bf16, append lora_up + zero pad ----------------
__global__ __launch_bounds__(256) void dequant_kernel(const int* __restrict__ qw,
                                                      const float* __restrict__ wscale,
                                                      const float* __restrict__ lu,
                                                      u16* __restrict__ B) {
  int o = blockIdx.x;
  int tid = threadIdx.x;
  const int4* qr = (const int4*)(qw + (size_t)o * IN_F);
  const float* sr = wscale + (size_t)o * (IN_F / 64);
  u16* Br = B + (size_t)o * KEXT;
#pragma unroll
  for (int s = 0; s < 4; ++s) {
    int e = tid + s * 256;
    int4 q = qr[e];
    float sc = sr[e >> 4];
    ushort4 u;
    u.x = f2bf((float)q.x * sc);
    u.y = f2bf((float)q.y * sc);
    u.z = f2bf((float)q.z * sc);
    u.w = f2bf((float)q.w * sc);
    *(ushort4*)(Br + (size_t)4 * e) = u;
  }
  if (tid < RANK) Br[IN_F + tid] = f2bf(lu[(size_t)o * RANK + tid]);
  if (tid < 8) {
    ushort4 z; z.x = z.y = z.z = z.w = 0;
    *(ushort4*)(Br + IN_F + 32 + tid * 4) = z;
  }
}

// ---------------- lorad: tr = x @ ld^T, split-K=8 partials ----------------
__global__ __launch_bounds__(256) void lorad_kernel(const float* __restrict__ x,
                                                    const float* __restrict__ ld,
                                                    float* __restrict__ tr8) {
  __shared__ float Xs[128][68];
  __shared__ float Ls[32][68];
  int b = blockIdx.x;
  int t0 = (b >> 3) * 128;
  int kbase = (b & 7) * 512;
  int tid = threadIdx.x;
  int rb = tid & 7;
  int tb = tid >> 3;
  float acc[4][4];
#pragma unroll
  for (int i = 0; i < 4; ++i)
#pragma unroll
    for (int j = 0; j < 4; ++j) acc[i][j] = 0.f;

  for (int kc = 0; kc < 512; kc += 64) {
    int k0 = kbase + kc;
    __syncthreads();
#pragma unroll
    for (int s = 0; s < 8; ++s) {
      int e = tid + s * 256;
      int row = e >> 4, c4 = (e & 15) * 4;
      float4 vv = *(const float4*)(x + (size_t)(t0 + row) * IN_F + k0 + c4);
      *(float4*)&Xs[row][c4] = vv;
    }
#pragma unroll
    for (int s = 0; s < 2; ++s) {
      int e = tid + s * 256;
      int row = e >> 4, c4 = (e & 15) * 4;
      float4 vv = *(const float4*)(ld + (size_t)row * IN_F + k0 + c4);
      *(float4*)&Ls[row][c4] = vv;
    }
    __syncthreads();
    for (int k4 = 0; k4 < 64; k4 += 4) {
      float4 lv[4], xv[4];
#pragma unroll
      for (int r = 0; r < 4; ++r) lv[r] = *(float4*)&Ls[rb + r * 8][k4];
#pragma unroll
      for (int mm = 0; mm < 4; ++mm) xv[mm] = *(float4*)&Xs[tb + mm * 32][k4];
#pragma unroll
      for (int mm = 0; mm < 4; ++mm)
#pragma unroll
        for (int r = 0; r < 4; ++r)
          acc[mm][r] += xv[mm].x * lv[r].x + xv[mm].y * lv[r].y +
                        xv[mm].z * lv[r].z + xv[mm].w * lv[r].w;
    }
  }
  float* dst = tr8 + (size_t)(b & 7) * NTOK * RANK;
#pragma unroll
  for (int mm = 0; mm < 4; ++mm)
#pragma unroll
    for (int r = 0; r < 4; ++r)
      dst[(size_t)(t0 + tb + mm * 32) * RANK + rb + r * 8] = acc[mm][r];
}

// ---------------- trwrite ----------------
__global__ __launch_bounds__(256) void trwrite_kernel(const float* __restrict__ tr8,
                                                      const float* __restrict__ ascale,
                                                      u16* __restrict__ A) {
  int idx = blockIdx.x * 256 + threadIdx.x;
  int t = idx >> 5, r = idx & 31;
  float s = 0.f;
#pragma unroll
  for (int k = 0; k < 8; ++k) s += tr8[(size_t)k * NTOK * RANK + idx];
  A[(size_t)t * KEXT + IN_F + r] = f2bf(s / ascale[t]);
}

// ---------------- main GEMM: 256x256 tile, BK=64, 8 waves, free-flow quadrant schedule ----------------
// LDS map (bytes): A buf c at c*32768; B buf c at 65536 + c*32768. Swizzle: 16B
// chunk u of row r holds global chunk u ^ (r&7); staging pre-swizzles the global
// source (involution), ds_read applies the same XOR -> 0 bank conflicts.
//
// Per K-tile: issue ALL 24 ds_read_b128 up front, then 4 MFMA quadrants with NO
// barrier between reads and MFMA -- compiler's in-order lgkmcnt(N) waits let the
// LDS pipe drain under the MFMA shadow (the round-3 structure serialized them).
// Hazard proof for mid-tile staging into the CURRENT buffer c:
//  - DS queue completes in order; Q1+Q2 consume af[0..7] => at the post-Q2
//    barrier every wave's A-region reads have completed -> stage A(t+2) safe.
//  - Q3 consumes bf[2..3] (last-issued reads) => post-Q3 barrier -> stage B safe.
//  - sched_barrier(0) before each s_barrier pins the register-only MFMAs (and
//    their lgkm waits) above the barrier (rule: MFMA can cross asm "memory").
//  - vmcnt(8) after stage-B + post-Q4 barrier sequences EVERY wave's t+1
//    landing before any wave's t+2 reads (vmcnt is per-wave).
// Barriers: 3/tile (was 8/tile).

__device__ __forceinline__ void stage_tile(const char* g, char* ldst, int tid) {
#pragma unroll
  for (int h = 0; h < 4; ++h)
    gload_lds16(g + (size_t)h * (64 * ROWB), ldst + h * 8192 + tid * 16);
}

#define PIN_BARRIER() do { __builtin_amdgcn_sched_barrier(0); \
                           asm volatile("s_barrier" ::: "memory"); } while (0)

__global__ __launch_bounds__(512, 2) void gemm_kernel(const u16* __restrict__ A,
                                                      const u16* __restrict__ B,
                                                      const float* __restrict__ ascale,
                                                      const float* __restrict__ bias,
                                                      float* __restrict__ out) {
  __shared__ __align__(16) char smem[131072];
  int b = blockIdx.x;
  int swz = (b & 7) * 32 + (b >> 3);     // 256 blocks, 8 XCDs -> bijective
  int by = swz >> 4, bx = swz & 15;
  int tm = by * 256, tn = bx * 256;
  int tid = threadIdx.x;
  int lane = tid & 63, wid = tid >> 6;
  int wr = wid >> 2, wc = wid & 3;       // 2x4 wave grid; wave owns 128x64 of C
  int l15 = lane & 15, l4 = lane >> 4;
  int xorb = (l15 & 7) << 4;             // row&7 -> 16B-chunk XOR (bits 4-6)
  int colx0 = (l4 * 16) ^ xorb;          // K elements l4*8 .. +7
  int colx1 = (l4 * 16 + 64) ^ xorb;     // K elements 32+l4*8 .. +7
  int a_base = wr * 16384 + l15 * 128;   // row = wr*128 + i*16 + l15
  int b_base = wc * 8192 + l15 * 128;    // row = wc*64 + j*16 + l15

  // staging: thread tid writes LDS bytes [h*8192 + tid*16); source column chunk
  // is (tid&7) ^ (row&7), row = tid>>3 within the 64-row h-block.
  int r0 = tid >> 3;
  int cb = (((tid & 7) ^ ((tid >> 3) & 7)) << 4);
  const char* ag = (const char*)A + (size_t)(tm + r0) * ROWB + cb;
  const char* bg = (const char*)B + (size_t)(tn + r0) * ROWB + cb;

  f32x4 acc[8][4];
#pragma unroll
  for (int i = 0; i < 8; ++i)
#pragma unroll
    for (int j = 0; j < 4; ++j) acc[i][j] = (f32x4){0.f, 0.f, 0.f, 0.f};

  // prologue: stage tiles 0 (buf0) and 1 (buf1)
  stage_tile(ag, smem, tid);
  stage_tile(bg, smem + 65536, tid);
  stage_tile(ag + 128, smem + 32768, tid);
  stage_tile(bg + 128, smem + 65536 + 32768, tid);
  asm volatile("s_waitcnt vmcnt(8)" ::: "memory");  // tile 0 landed; tile 1 in flight
  PIN_BARRIER();

  const char* apf = ag + 256;  // tile t+2 source (t=0)
  const char* bpf = bg + 256;
  bf16x8 af[8][2], bf[4][2];

  for (int t = 0; t < NT; ++t) {
    int c = t & 1;
    int ao = c * 32768 + a_base;
    int bo = 65536 + c * 32768 + b_base;
    bool pf = (t + 2) < NT;

    // ---- issue all fragment reads (order matters for the in-order drain proof) ----
#pragma unroll
    for (int i = 0; i < 4; ++i) {
      af[i][0] = *(const bf16x8*)(smem + ao + i * 2048 + colx0);
      af[i][1] = *(const bf16x8*)(smem + ao + i * 2048 + colx1);
    }
#pragma unroll
    for (int j = 0; j < 2; ++j) {
      bf[j][0] = *(const bf16x8*)(smem + bo + j * 2048 + colx0);
      bf[j][1] = *(const bf16x8*)(smem + bo + j * 2048 + colx1);
    }
#pragma unroll
    for (int i = 4; i < 8; ++i) {
      af[i][0] = *(const bf16x8*)(smem + ao + i * 2048 + colx0);
      af[i][1] = *(const bf16x8*)(smem + ao + i * 2048 + colx1);
    }
#pragma unroll
    for (int j = 2; j < 4; ++j) {
      bf[j][0] = *(const bf16x8*)(smem + bo + j * 2048 + colx0);
      bf[j][1] = *(const bf16x8*)(smem + bo + j * 2048 + colx1);
    }

    // ---- Q1: m0-3 x n0-1 ----
    __builtin_amdgcn_s_setprio(1);
#pragma unroll
    for (int i = 0; i < 4; ++i)
#pragma unroll
      for (int j = 0; j < 2; ++j) {
        acc[i][j] = __builtin_amdgcn_mfma_f32_16x16x32_bf16(af[i][0], bf[j][0], acc[i][j], 0, 0, 0);
        acc[i][j] = __builtin_amdgcn_mfma_f32_16x16x32_bf16(af[i][1], bf[j][1], acc[i][j], 0, 0, 0);
      }
    __builtin_amdgcn_s_setprio(0);

    // ---- Q2: m4-7 x n0-1 (consumes af[4..7] => all A reads drained after this) ----
    __builtin_amdgcn_s_setprio(1);
#pragma unroll
    for (int i = 4; i < 8; ++i)
#pragma unroll
      for (int j = 0; j < 2; ++j) {
        acc[i][j] = __builtin_amdgcn_mfma_f32_16x16x32_bf16(af[i][0], bf[j][0], acc[i][j], 0, 0, 0);
        acc[i][j] = __builtin_amdgcn_mfma_f32_16x16x32_bf16(af[i][1], bf[j][1], acc[i][j], 0, 0, 0);
      }
    __builtin_amdgcn_s_setprio(0);
    PIN_BARRIER();                         // A-region of buf c free in ALL waves
    if (pf) stage_tile(apf, smem + c * 32768, tid);

    // ---- Q3: m0-3 x n2-3 (consumes bf[2..3] => all reads drained after this) ----
    __builtin_amdgcn_s_setprio(1);
#pragma unroll
    for (int i = 0; i < 4; ++i)
#pragma unroll
      for (int j = 2; j < 4; ++j) {
        acc[i][j] = __builtin_amdgcn_mfma_f32_16x16x32_bf16(af[i][0], bf[j][0], acc[i][j], 0, 0, 0);
        acc[i][j] = __builtin_amdgcn_mfma_f32_16x16x32_bf16(af[i][1], bf[j][1], acc[i][j], 0, 0, 0);
      }
    __builtin_amdgcn_s_setprio(0);
    PIN_BARRIER();                         // B-region of buf c free in ALL waves
    if (pf) {
      stage_tile(bpf, smem + 65536 + c * 32768, tid);
      asm volatile("s_waitcnt vmcnt(8)" ::: "memory");  // t+1 landed; t+2 in flight
    } else if (t == NT - 2) {
      asm volatile("s_waitcnt vmcnt(0)" ::: "memory");  // tail drain for tile NT-1
    }

    // ---- Q4: m4-7 x n2-3 ----
    __builtin_amdgcn_s_setprio(1);
#pragma unroll
    for (int i = 4; i < 8; ++i)
#pragma unroll
      for (int j = 2; j < 4; ++j) {
        acc[i][j] = __builtin_amdgcn_mfma_f32_16x16x32_bf16(af[i][0], bf[j][0], acc[i][j], 0, 0, 0);
        acc[i][j] = __builtin_amdgcn_mfma_f32_16x16x32_bf16(af[i][1], bf[j][1], acc[i][j], 0, 0, 0);
      }
    __builtin_amdgcn_s_setprio(0);
    PIN_BARRIER();                         // all waves saw their vmcnt before t+1 reads

    apf += 128;
    bpf += 128;
  }

  // ---- epilogue: C = acc * ascale[row] + bias[col] ----
#pragma unroll
  for (int i = 0; i < 8; ++i) {
    int rowb = tm + wr * 128 + i * 16 + l4 * 4;
#pragma unroll
    for (int j = 0; j < 4; ++j) {
      int col = tn + wc * 64 + j * 16 + l15;
      float bv = bias[col];
#pragma unroll
      for (int q = 0; q < 4; ++q)
        out[(size_t)(rowb + q) * OUT_F + col] = acc[i][j][q] * ascale[rowb + q] + bv;
    }
  }
}

extern "C" void kernel_launch(void* const* d_in, const int* in_sizes, int n_in,
                              void* d_out, int out_size, void* d_ws, size_t ws_size,
                              hipStream_t stream) {
  const float* x = (const float*)d_in[0];
  const int* qw = (const int*)d_in[1];
  const float* wscale = (const float*)d_in[2];
  const float* ld = (const float*)d_in[3];
  const float* lu = (const float*)d_in[4];
  const float* bias = (const float*)d_in[5];
  float* out = (float*)d_out;

  char* ws = (char*)d_ws;
  const size_t szA = (size_t)NTOK * KEXT * sizeof(u16);
  const size_t szB = (size_t)OUT_F * KEXT * sizeof(u16);
  u16* Aext = (u16*)ws;
  u16* Bext = (u16*)(ws + szA);
  float* ascale = (float*)(ws + szA + szB);
  float* tr8 = (float*)(ws + szA + szB + 16384);

  prep_kernel<<<NTOK, 256, 0, stream>>>(x, Aext, ascale);
  dequant_kernel<<<OUT_F, 256, 0, stream>>>(qw, wscale, lu, Bext);
  lorad_kernel<<<256, 256, 0, stream>>>(x, ld, tr8);
  trwrite_kernel<<<NTOK * RANK / 256, 256, 0, stream>>>(tr8, ascale, Aext);
  gemm_kernel<<<(NTOK / 256) * (OUT_F / 256), 512, 0, stream>>>(Aext, Bext, ascale, bias, out);
}